// Round 7
// baseline (235.088 us; speedup 1.0000x reference)
//
#include <hip/hip_runtime.h>
#include <hip/hip_bf16.h>

// SNN IF scan, T=4. Memory-bound: 134 MB in + 134 MB out (~43 us floor at
// copy rate). History: serialized loads (R0/R2/R5, VGPR<=32) = ~82 us; R4
// 16-deep nt batch = ~70 us; R6 32-deep nt batch, consume-order issue =
// ~67 us (4.0 TB/s combined).
// R7 single-variable test: PLAIN loads (keep nt stores). Rationale: harness
// restore-copy leaves ~half of x LLC-resident (plain-load rounds all showed
// FETCH=65 MB = half of input from LLC). nt loads mark lines
// evict-first/no-allocate and may bypass LLC service entirely -> R6 might be
// fetching the full 134 MB from HBM, i.e. HBM-saturated on avoidable reads.
// Everything else identical to R6 (32 loads issued in consume order,
// sched_barrier pins the batch, progressive vmcnt drain).

#define T_STEPS 4
#define UNROLL 8

typedef float vfloat4 __attribute__((ext_vector_type(4)));

__global__ __launch_bounds__(256) void IF_18622978195596_kernel(
    const vfloat4* __restrict__ x, const float* __restrict__ thresh_p,
    vfloat4* __restrict__ out, int n4) {
    // n4 = 2^21 divides exactly by 256*UNROLL = 2048; no guards.
    const int base = blockIdx.x * (256 * UNROLL) + threadIdx.x;
    const float th = *thresh_p;

    // ---- load phase: 32 independent cached loads, issued in consume order ----
    vfloat4 xv[UNROLL][T_STEPS];
#pragma unroll
    for (int u = 0; u < UNROLL; ++u) {
        const int i = base + u * 256;
#pragma unroll
        for (int t = 0; t < T_STEPS; ++t) {
            xv[u][t] = x[(size_t)t * n4 + i];
        }
    }
    // pin the batch: nothing crosses this point
    __builtin_amdgcn_sched_barrier(0);

    // ---- consume phase, in issue order -> progressive vmcnt drain ----
#pragma unroll
    for (int u = 0; u < UNROLL; ++u) {
        const int i = base + u * 256;
        vfloat4 mem = {0.5f * th, 0.5f * th, 0.5f * th, 0.5f * th};
#pragma unroll
        for (int t = 0; t < T_STEPS; ++t) {
            mem += xv[u][t];
            vfloat4 s;
            s.x = (mem.x >= th) ? th : 0.0f;
            s.y = (mem.y >= th) ? th : 0.0f;
            s.z = (mem.z >= th) ? th : 0.0f;
            s.w = (mem.w >= th) ? th : 0.0f;
            mem -= s;
            __builtin_nontemporal_store(s, &out[(size_t)t * n4 + i]);
        }
    }
}

extern "C" void kernel_launch(void* const* d_in, const int* in_sizes, int n_in,
                              void* d_out, int out_size, void* d_ws, size_t ws_size,
                              hipStream_t stream) {
    const float* x = (const float*)d_in[0];
    const float* thresh = (const float*)d_in[1];
    float* out = (float*)d_out;

    int total = in_sizes[0];              // 33,554,432 floats
    int n_per_t = total / T_STEPS;        // 8,388,608 neurons
    int n4 = n_per_t / 4;                 // 2,097,152 vfloat4 per timestep

    int block = 256;
    int per_block = block * UNROLL;       // 2048 vfloat4 per block per t
    int grid = n4 / per_block;            // 1024 blocks = 4 per CU, exact
    IF_18622978195596_kernel<<<grid, block, 0, stream>>>(
        (const vfloat4*)x, thresh, (vfloat4*)out, n4);
}